// Round 1
// baseline (162.831 us; speedup 1.0000x reference)
//
#include <hip/hip_runtime.h>
#include <math.h>

#define BB 4
#define TT 2048
#define TTP 2112   // TT + 64 zero pad rows per head (pe)
#define NEMB 256
#define NH 8
#define HD 32

typedef __attribute__((ext_vector_type(8))) short bf8;   // 8 x bf16 (4 VGPRs)
typedef __attribute__((ext_vector_type(4))) float f4;    // MFMA C/D

static __device__ __forceinline__ unsigned short f2bf(float f) {
    union { float f; unsigned u; } v; v.f = f;
    unsigned r = v.u + 0x7FFF + ((v.u >> 16) & 1);       // RNE
    return (unsigned short)(r >> 16);
}
static __device__ __forceinline__ float bf2f(unsigned short s) {
    union { unsigned u; float f; } v; v.u = ((unsigned)s) << 16;
    return v.f;
}

// DPP cross-lane move within 16-lane rows (VALU pipe)
template <int CTRL>
static __device__ __forceinline__ float dppmv(float x) {
    return __int_as_float(__builtin_amdgcn_mov_dpp(__float_as_int(x), CTRL, 0xF, 0xF, true));
}
static __device__ __forceinline__ float rowsum16(float x) {
    x += dppmv<0xB1>(x);
    x += dppmv<0x4E>(x);
    x += dppmv<0x124>(x);
    x += dppmv<0x128>(x);
    return x;
}

// ---------------- fused prep: pe->bf16 (+zero pad), w_attn^T, w_proj^T -------
static __device__ __forceinline__ void tcvt_body(const float* __restrict__ src,
                                                 unsigned short* __restrict__ dst,
                                                 int R, int C, int gx, int gy,
                                                 float (*t)[65], int tid) {
    const int c0 = gx * 64, r0 = gy * 64;
    #pragma unroll
    for (int p = 0; p < 4; ++p) {
        const int i = tid + p * 256;
        const int r = i >> 4, c4 = (i & 15) * 4;
        const float4 v = *(const float4*)(src + (long)(r0 + r) * C + c0 + c4);
        t[r][c4] = v.x; t[r][c4+1] = v.y; t[r][c4+2] = v.z; t[r][c4+3] = v.w;
    }
    __syncthreads();
    #pragma unroll
    for (int p = 0; p < 4; ++p) {
        const int i = tid + p * 256;
        const int cr = i >> 4, r4 = (i & 15) * 4;
        ushort4 vv;
        vv.x = f2bf(t[r4+0][cr]); vv.y = f2bf(t[r4+1][cr]);
        vv.z = f2bf(t[r4+2][cr]); vv.w = f2bf(t[r4+3][cr]);
        *(ushort4*)(dst + (long)(c0 + cr) * R + r0 + r4) = vv;
    }
}

__global__ __launch_bounds__(256) void prep(const float* __restrict__ pe,
                                            unsigned short* __restrict__ peb,
                                            const float* __restrict__ wa,
                                            unsigned short* __restrict__ waT,
                                            const float* __restrict__ wp,
                                            unsigned short* __restrict__ wpT) {
    __shared__ float t[64][65];
    const int bx = blockIdx.x, tid = threadIdx.x;
    if (bx < 528) {                              // pe [8][2048][32] -> [8][2112][32] bf16, pad=0
        const int idx4 = bx * 256 + tid;         // ushort4 granules over [8][2112][8]
        const int h   = idx4 / 16896;
        const int rem = idx4 - h * 16896;
        const int u   = rem >> 3;
        const int d4  = (rem & 7) * 4;
        ushort4 o = make_ushort4(0, 0, 0, 0);
        if (u < TT) {
            const float4 v = *(const float4*)(pe + ((long)(h * TT + u)) * HD + d4);
            o.x = f2bf(v.x); o.y = f2bf(v.y); o.z = f2bf(v.z); o.w = f2bf(v.w);
        }
        *(ushort4*)(peb + ((long)(h * TTP + u)) * HD + d4) = o;
    } else if (bx < 576) {
        const int lo = bx - 528;                 // 48 blocks: w_attn [256][768] -> [768][256]
        tcvt_body(wa, waT, 256, 768, lo % 12, lo / 12, t, tid);
    } else {
        const int lo = bx - 576;                 // 16 blocks: w_proj transpose
        tcvt_body(wp, wpT, 256, 256, lo % 4, lo / 4, t, tid);
    }
}

// ---------------- Kernel A: MFMA qkv GEMM, fp32 A inline-converted -----------
// Q pre-scaled by (1/sqrt(32)) * log2(e) so attention uses raw exp2.
__global__ __launch_bounds__(256) void qkv_mfma(const float* __restrict__ xg,
                                                const unsigned short* __restrict__ Bg,
                                                unsigned short* __restrict__ Kb,
                                                unsigned short* __restrict__ Qb,
                                                unsigned short* __restrict__ Vt) {
    __shared__ unsigned short sm[13824];             // 27648 B
    unsigned short* As = sm;                         // [128][72]
    unsigned short* Bs = sm + 9216;                  // [64][72]
    const int tid = threadIdx.x;
    const int wv = tid >> 6, L = tid & 63;
    const int l15 = L & 15, q = L >> 4;
    const int n0 = blockIdx.x * 64;
    const int m0 = blockIdx.y * 128;

    f4 acc[2][4];
    #pragma unroll
    for (int mt = 0; mt < 2; ++mt)
        #pragma unroll
        for (int nt = 0; nt < 4; ++nt) acc[mt][nt] = (f4){0.f,0.f,0.f,0.f};

    for (int kc = 0; kc < 4; ++kc) {
        const int k0 = kc * 64;
        __syncthreads();
        #pragma unroll
        for (int p = 0; p < 4; ++p) {
            const int i = tid + p * 256;
            const int r = i >> 3, c = i & 7;
            const float4 va = *(const float4*)(xg + (long)(m0 + r) * 256 + k0 + c * 8);
            const float4 vb = *(const float4*)(xg + (long)(m0 + r) * 256 + k0 + c * 8 + 4);
            ushort4 lo, hi;
            lo.x = f2bf(va.x); lo.y = f2bf(va.y); lo.z = f2bf(va.z); lo.w = f2bf(va.w);
            hi.x = f2bf(vb.x); hi.y = f2bf(vb.y); hi.z = f2bf(vb.z); hi.w = f2bf(vb.w);
            *(ushort4*)(As + r * 72 + c * 8)     = lo;
            *(ushort4*)(As + r * 72 + c * 8 + 4) = hi;
        }
        #pragma unroll
        for (int p = 0; p < 2; ++p) {
            const int i = tid + p * 256;
            const int r = i >> 3, c = i & 7;
            *(bf8*)(Bs + r * 72 + c * 8) = *(const bf8*)(Bg + (long)(n0 + r) * 256 + k0 + c * 8);
        }
        __syncthreads();
        #pragma unroll
        for (int kk = 0; kk < 2; ++kk) {
            const bf8 a0 = *(const bf8*)(As + (wv * 32 + l15) * 72 + kk * 32 + q * 8);
            const bf8 a1 = *(const bf8*)(As + (wv * 32 + 16 + l15) * 72 + kk * 32 + q * 8);
            #pragma unroll
            for (int nt = 0; nt < 4; ++nt) {
                const bf8 bb = *(const bf8*)(Bs + (nt * 16 + l15) * 72 + kk * 32 + q * 8);
                acc[0][nt] = __builtin_amdgcn_mfma_f32_16x16x32_bf16(a0, bb, acc[0][nt], 0, 0, 0);
                acc[1][nt] = __builtin_amdgcn_mfma_f32_16x16x32_bf16(a1, bb, acc[1][nt], 0, 0, 0);
            }
        }
    }

    const int sec = n0 >> 8;                         // 0=K,1=Q,2=V
    #pragma unroll
    for (int mt = 0; mt < 2; ++mt) {
        const int gm = m0 + wv * 32 + mt * 16 + q * 4;
        const int b = gm >> 11, tb = gm & 2047;
        #pragma unroll
        for (int nt = 0; nt < 4; ++nt) {
            const int gn = n0 + nt * 16 + l15;
            const int cc = gn & 255, h = cc >> 5, d = cc & 31;
            const long bh = (long)b * NH + h;
            const f4 a = acc[mt][nt];
            if (sec == 2) {
                ushort4 vv;
                vv.x = f2bf(a[0]); vv.y = f2bf(a[1]); vv.z = f2bf(a[2]); vv.w = f2bf(a[3]);
                *(ushort4*)(Vt + (bh * HD + d) * TT + tb) = vv;
            } else if (sec == 1) {
                #pragma unroll
                for (int r = 0; r < 4; ++r)
                    Qb[(bh * TT + tb + r) * HD + d] = f2bf(a[r] * 0.25506655788696527f);
            } else {
                #pragma unroll
                for (int r = 0; r < 4; ++r)
                    Kb[(bh * TT + tb + r) * HD + d] = f2bf(a[r]);
            }
        }
    }
}

// ---------------- Kernel B: MFMA flash attention, static-max softmax ---------
// Merged-halves version: one jt loop processes BOTH t-tiles (pair, 31-pair),
// sharing Ks/Vts staging + bk/bv fragment reads in the overlap region.
// Psw stride 76 (conflict-free b16 scatter); 12-bpermute skew gather.

static __device__ __forceinline__ void finish_tile(
    f4* sa, const bf8 aq, const unsigned short* __restrict__ PEs,
    unsigned short* __restrict__ Psw, bool diag,
    const bf8 bv00, const bf8 bv01, const bf8 bv10, const bf8 bv11,
    f4& o0, f4& o1, float* l_st,
    const int* saddr, const unsigned* pselL, const unsigned* pselX,
    int wv, int l15, int q)
{
    const f4 z4 = {0.f, 0.f, 0.f, 0.f};
    const int pebase = 48 - 16 * wv;
    f4 ra[5];
    #pragma unroll
    for (int nt = 0; nt < 5; ++nt) {
        const bf8 bp = *(const bf8*)(PEs + (pebase + nt * 16 + l15) * 40 + q * 8);
        ra[nt] = __builtin_amdgcn_mfma_f32_16x16x32_bf16(aq, bp, z4, 0, 0, 0);
    }

    // ---- skew gather: 3 packed words per r serve all 4 nb ----
    #pragma unroll
    for (int r = 0; r < 4; ++r) {
        const unsigned w0 = __builtin_amdgcn_perm(
            (unsigned)__float_as_int(ra[1][r]), (unsigned)__float_as_int(ra[0][r]), 0x07060302u);
        const unsigned w1 = __builtin_amdgcn_perm(
            (unsigned)__float_as_int(ra[3][r]), (unsigned)__float_as_int(ra[2][r]), 0x07060302u);
        const unsigned w2 = ((unsigned)__float_as_int(ra[4][r])) >> 16;
        const int v0 = __builtin_amdgcn_ds_bpermute(saddr[r], (int)w0);
        const int v1 = __builtin_amdgcn_ds_bpermute(saddr[r], (int)w1);
        const int v2 = __builtin_amdgcn_ds_bpermute(saddr[r], (int)w2);
        sa[0][r] += __int_as_float((int)__builtin_amdgcn_perm((unsigned)v0, (unsigned)v0, pselL[r]));
        sa[1][r] += __int_as_float((int)__builtin_amdgcn_perm((unsigned)v1, (unsigned)v0, pselX[r]));
        sa[2][r] += __int_as_float((int)__builtin_amdgcn_perm((unsigned)v1, (unsigned)v1, pselL[r]));
        sa[3][r] += __int_as_float((int)__builtin_amdgcn_perm((unsigned)v2, (unsigned)v1, pselX[r]));
    }

    if (diag) {                                  // causal mask (diagonal tile)
        #pragma unroll
        for (int nb = 0; nb < 4; ++nb)
            #pragma unroll
            for (int r = 0; r < 4; ++r) {
                const int s_l = nb * 16 + l15;
                const int t_l = wv * 16 + 4 * q + r;
                if (s_l > t_l) sa[nb][r] = -1e30f;
            }
    }

    // ---- static-max softmax: p = exp2(sa); accumulate l per lane ----
    #pragma unroll
    for (int r = 0; r < 4; ++r) {
        #pragma unroll
        for (int nb = 0; nb < 4; ++nb) {
            const float p = exp2f(sa[nb][r]);
            l_st[r] += p;
            const unsigned pu = (unsigned)__float_as_int(p);
            Psw[(4 * q + r) * 76 + nb * 16 + l15] =
                (unsigned short)((pu + 0x8000u) >> 16);
        }
    }

    // ---- PV: O += P @ V ----
    #pragma unroll
    for (int ks = 0; ks < 2; ++ks) {
        const bf8 ap = *(const bf8*)(Psw + l15 * 76 + ks * 32 + q * 8);
        o0 = __builtin_amdgcn_mfma_f32_16x16x32_bf16(ap, ks ? bv10 : bv00, o0, 0, 0, 0);
        o1 = __builtin_amdgcn_mfma_f32_16x16x32_bf16(ap, ks ? bv11 : bv01, o1, 0, 0, 0);
    }
}

__global__ __launch_bounds__(256) void attn_kernel(const unsigned short* __restrict__ Kb,
                                                   const unsigned short* __restrict__ Qb,
                                                   const unsigned short* __restrict__ Vtg,
                                                   const unsigned short* __restrict__ peb,
                                                   unsigned short* __restrict__ po,
                                                   float* __restrict__ pl) {
    __shared__ unsigned short lds[19968];            // 39936 B
    unsigned short* Ks   = lds;                      // [64][40]  K tile
    unsigned short* PEsB = lds + 2560;               // [128][40] pe band, big tile
    unsigned short* PEsA = lds + 7680;               // [128][40] pe band, small tile
    unsigned short* Vts  = lds + 12800;              // [32][72]  V^T tile
    unsigned short* Psw  = lds + 15104 + (threadIdx.x >> 6) * 1216;  // [16][76] per wave

    const int tid = threadIdx.x;
    const int wv  = tid >> 6;
    const int L   = tid & 63;
    const int l15 = L & 15;
    const int q   = L >> 4;
    const int pair = blockIdx.x >> 1;
    const int sblk = blockIdx.x & 1;
    const int h = blockIdx.y, b = blockIdx.z;
    const long bh = (long)b * NH + h;
    const unsigned short* Kg = Kb  + bh * TT * HD;
    const unsigned short* Qg = Qb  + bh * TT * HD;
    const unsigned short* Vg = Vtg + bh * HD * TT;
    const unsigned short* Pg = peb + (long)h * TTP * HD;

    const int krow = tid >> 2, kc = tid & 3;
    const int vrow = tid >> 3, vc = tid & 7;
    const f4 z4 = {0.f, 0.f, 0.f, 0.f};
    const f4 m4 = {-16.f, -16.f, -16.f, -16.f};      // static softmax max

    // hoisted skew-gather controls (per r): source lane + perm half-selects
    int saddr[4]; unsigned pselL[4], pselX[4];
    #pragma unroll
    for (int r = 0; r < 4; ++r) {
        const int tcol = l15 + 15 - 4 * q - r;       // 0..30
        saddr[r] = ((q << 4) | (tcol & 15)) << 2;
        const bool c = tcol >= 16;
        pselL[r] = c ? 0x03020C0Cu : 0x01000C0Cu;    // intra-word: hi : lo
        pselX[r] = c ? 0x05040C0Cu : 0x03020C0Cu;    // cross-word: a.lo : b.hi
    }

    const int iA = pair, iB = 31 - pair;
    const int t0A = iA * 64, t0B = iB * 64;

    const bf8 aqA = *(const bf8*)(Qg + (t0A + wv * 16 + l15) * HD + q * 8);
    const bf8 aqB = *(const bf8*)(Qg + (t0B + wv * 16 + l15) * HD + q * 8);

    f4 oA0 = z4, oA1 = z4, oB0 = z4, oB1 = z4;
    float lA[4] = {0.f, 0.f, 0.f, 0.f}, lB[4] = {0.f, 0.f, 0.f, 0.f};

    for (int jt = sblk; jt <= iB; jt += 2) {
        const int s0 = jt * 64;
        const bool actA = (jt <= iA);
        __syncthreads();
        *(bf8*)(Ks  + krow * 40 + kc * 8) = *(const bf8*)(Kg + (s0 + krow) * HD + kc * 8);
        *(bf8*)(Vts + vrow * 72 + vc * 8) = *(const bf8*)(Vg + vrow * TT + s0 + vc * 8);
        const int ubB = TT - 64 - t0B + s0;
        #pragma unroll
        for (int kk = 0; kk < 2; ++kk) {
            const int i  = tid + kk * 256;
            const int pr = i >> 2, pc = i & 3;
            *(bf8*)(PEsB + pr * 40 + pc * 8) = *(const bf8*)(Pg + (long)(ubB + pr) * HD + pc * 8);
        }
        if (actA) {
            const int ubA = TT - 64 - t0A + s0;
            #pragma unroll
            for (int kk = 0; kk < 2; ++kk) {
                const int i  = tid + kk * 256;
                const int pr = i >> 2, pc = i & 3;
                *(bf8*)(PEsA + pr * 40 + pc * 8) = *(const bf8*)(Pg + (long)(ubA + pr) * HD + pc * 8);
            }
        }
        __syncthreads();

        // QK for both tiles sharing the K fragment reads
        f4 saA[4], saB[4];
        #pragma unroll
        for (int nt = 0; nt < 4; ++nt) {
            const bf8 bk = *(const bf8*)(Ks + (nt * 16 + l15) * 40 + q * 8);
            saB[nt] = __builtin_amdgcn_mfma_f32_16x16x32_bf16(aqB, bk, m4, 0, 0, 0);
            if (actA)
                saA[nt] = __builtin_amdgcn_mfma_f32_16x16x32_bf16(aqA, bk, m4, 0, 0, 0);
        }

        // V fragments shared by both tiles
        const bf8 bv00 = *(const bf8*)(Vts + l15 * 72 + q * 8);
        const bf8 bv01 = *(const bf8*)(Vts + (16 + l15) * 72 + q * 8);
        const bf8 bv10 = *(const bf8*)(Vts + l15 * 72 + 32 + q * 8);
        const bf8 bv11 = *(const bf8*)(Vts + (16 + l15) * 72 + 32 + q * 8);

        finish_tile(saB, aqB, PEsB, Psw, jt == iB, bv00, bv01, bv10, bv11,
                    oB0, oB1, lB, saddr, pselL, pselX, wv, l15, q);
        if (actA)
            finish_tile(saA, aqA, PEsA, Psw, jt == iA, bv00, bv01, bv10, bv11,
                        oA0, oA1, lA, saddr, pselL, pselX, wv, l15, q);
    }

    // ---- epilogue: raw partial O (bf16) + row l, for both tiles ----
    {
        const long pt = (bh * 32 + iB) * 2 + sblk;
        unsigned short* pob = po + pt * 2048;
        #pragma unroll
        for (int r = 0; r < 4; ++r) {
            const int row = wv * 16 + 4 * q + r;
            pob[row * 32 + l15]      = f2bf(oB0[r]);
            pob[row * 32 + 16 + l15] = f2bf(oB1[r]);
            const float ls = rowsum16(lB[r]);
            if (l15 == 0) pl[pt * 64 + row] = ls;
        }
    }
    {
        const long pt = (bh * 32 + iA) * 2 + sblk;
        unsigned short* pob = po + pt * 2048;
        #pragma unroll
        for (int r = 0; r < 4; ++r) {
            const int row = wv * 16 + 4 * q + r;
            pob[row * 32 + l15]      = f2bf(oA0[r]);
            pob[row * 32 + 16 + l15] = f2bf(oA1[r]);
            const float ls = rowsum16(lA[r]);
            if (l15 == 0) pl[pt * 64 + row] = ls;
        }
    }
}

// ---------------- merge s-split partials -> bf16 att -------------------------
__global__ __launch_bounds__(256) void attn_merge(const unsigned short* __restrict__ po,
                                                  const float* __restrict__ pl,
                                                  unsigned short* __restrict__ attb) {
    const int i = blockIdx.x * 256 + threadIdx.x;    // 524288 quads
    const int d4   = i & 7;
    const int row  = (i >> 3) & 63;
    const int tile = (i >> 9) & 31;
    const int bh   = i >> 14;
    const int h = bh & 7, b = bh >> 3;
    const long pt0 = ((long)bh * 32 + tile) * 2;
    const float l0 = pl[pt0 * 64 + row], l1 = pl[(pt0 + 1) * 64 + row];
    const float inv = 1.0f / (l0 + l1);
    const ushort4 a = *(const ushort4*)(po + pt0 * 2048 + row * 32 + d4 * 4);
    const ushort4 c = *(const ushort4*)(po + (pt0 + 1) * 2048 + row * 32 + d4 * 4);
    ushort4 o;
    o.x = f2bf((bf2f(a.x) + bf2f(c.x)) * inv);
    o.y = f2bf((bf2f(a.y) + bf2f(c.y)) * inv);
    o.z = f2bf((bf2f(a.z) + bf2f(c.z)) * inv);
    o.w = f2bf((bf2f(a.w) + bf2f(c.w)) * inv);
    const int t = tile * 64 + row;
    *(ushort4*)(attb + ((long)(b * TT + t)) * NEMB + h * HD + d4 * 4) = o;
}

// ---------------- Kernel C: MFMA proj GEMM + bias ----------------------------
__global__ __launch_bounds__(256) void proj_mfma(const unsigned short* __restrict__ Ag,
                                                 const unsigned short* __restrict__ Bg,
                                                 const float* __restrict__ bias,
                                                 float* __restrict__ out) {
    __shared__ unsigned short sm[13824];
    unsigned short* As = sm;                         // [128][72]
    unsigned short* Bs = sm + 9216;                  // [64][72]
    const int tid = threadIdx.x;
    const int wv = tid >> 6, L = tid & 63;
    const int l15 = L & 15, q = L >> 4;
    const int n0 = blockIdx.x * 64;
    const int m0 = blockIdx.y * 128;

    f4 acc[2][4];
    #pragma unroll
    for (int mt = 0; mt < 2; ++mt)
        #pragma unroll
        for (int nt = 0; nt < 4; ++nt) acc[mt][nt] = (f4){0.f,0.f,0.f,0.f};

    for (int kc = 0; kc < 4; ++kc) {
        const int k0 = kc * 64;
        __syncthreads();
        #pragma unroll
        for (int p = 0; p < 4; ++p) {
            const int i = tid + p * 256;
            const int r = i >> 3, c = i & 7;
            *(bf8*)(As + r * 72 + c * 8) = *(const bf8*)(Ag + (long)(m0 + r) * 256 + k0 + c * 8);
        }
        #pragma unroll
        for (int p = 0; p < 2; ++p) {
            const int i = tid + p * 256;
            const int r = i >> 3, c = i & 7;
            *(bf8*)(Bs + r * 72 + c * 8) = *(const bf8*)(Bg + (long)(n0 + r) * 256 + k0 + c * 8);
        }
        __syncthreads();
        #pragma unroll
        for (int kk = 0; kk < 2; ++kk) {
            const bf8 a0 = *(const bf8*)(As + (wv * 32 + l15) * 72 + kk * 32 + q * 8);
            const bf8 a1 = *(const bf8*)(As + (wv * 32 + 16 + l15) * 72 + kk * 32 + q * 8);
            #pragma unroll
            for (int nt = 0; nt < 4; ++nt) {
                const bf8 bb = *(const bf8*)(Bs + (nt * 16 + l15) * 72 + kk * 32 + q * 8);
                acc[0][nt] = __builtin_amdgcn_mfma_f32_16x16x32_bf16(a0, bb, acc[0][nt], 0, 0, 0);
                acc[1][nt] = __builtin_amdgcn_mfma_f32_16x16x32_bf16(a1, bb, acc[1][nt], 0, 0, 0);
            }
        }
    }

    #pragma unroll
    for (int mt = 0; mt < 2; ++mt) {
        const int gm = m0 + wv * 32 + mt * 16 + q * 4;
        #pragma unroll
        for (int nt = 0; nt < 4; ++nt) {
            const int gn = n0 + nt * 16 + l15;
            const float bv = bias[gn];
            #pragma unroll
            for (int r = 0; r < 4; ++r)
                out[(long)(gm + r) * NEMB + gn] = acc[mt][nt][r] + bv;
        }
    }
}

extern "C" void kernel_launch(void* const* d_in, const int* in_sizes, int n_in,
                              void* d_out, int out_size, void* d_ws, size_t ws_size,
                              hipStream_t stream) {
    const float* x      = (const float*)d_in[0];
    const float* w_attn = (const float*)d_in[1];
    const float* pe     = (const float*)d_in[2];
    const float* w_proj = (const float*)d_in[3];
    const float* b_proj = (const float*)d_in[4];
    float* out = (float*)d_out;

    char* base = (char*)d_ws;
    unsigned short* Kb   = (unsigned short*)(base);                        // 4 MB
    unsigned short* Qb   = (unsigned short*)(base + ( 4u << 20));          // 4 MB
    unsigned short* Vt   = (unsigned short*)(base + ( 8u << 20));          // 4 MB
    unsigned short* attb = (unsigned short*)(base + (12u << 20));          // 4 MB
    unsigned short* peb  = (unsigned short*)(base + (16u << 20));          // 1.03 MB
    unsigned short* waT  = (unsigned short*)(base + (18u << 20));          // 384 KB
    unsigned short* wpT  = (unsigned short*)(base + (37u << 19));          // 128 KB @18.5MB
    unsigned short* po   = (unsigned short*)(base + (19u << 20));          // 8 MB
    float*          pl   = (float*)        (base + (27u << 20));           // 512 KB

    prep<<<dim3(592), 256, 0, stream>>>(pe, peb, w_attn, waT, w_proj, wpT);
    qkv_mfma<<<dim3(12, 64), 256, 0, stream>>>(x, waT, Kb, Qb, Vt);
    attn_kernel<<<dim3(32, NH, BB), 256, 0, stream>>>(Kb, Qb, Vt, peb, po, pl);
    attn_merge<<<dim3(2048), 256, 0, stream>>>(po, pl, attb);
    proj_mfma<<<dim3(4, 64), 256, 0, stream>>>(attb, wpT, b_proj, out);
}

// Round 2
// 156.204 us; speedup vs baseline: 1.0424x; 1.0424x over previous
//
#include <hip/hip_runtime.h>
#include <math.h>

#define BB 4
#define TT 2048
#define TTP 2112   // TT + 64 zero pad rows per head (pe)
#define NEMB 256
#define NH 8
#define HD 32

typedef __attribute__((ext_vector_type(8))) short bf8;   // 8 x bf16 (4 VGPRs)
typedef __attribute__((ext_vector_type(4))) float f4;    // MFMA C/D

static __device__ __forceinline__ unsigned short f2bf(float f) {
    union { float f; unsigned u; } v; v.f = f;
    unsigned r = v.u + 0x7FFF + ((v.u >> 16) & 1);       // RNE
    return (unsigned short)(r >> 16);
}
static __device__ __forceinline__ float bf2f(unsigned short s) {
    union { unsigned u; float f; } v; v.u = ((unsigned)s) << 16;
    return v.f;
}

// DPP cross-lane move within 16-lane rows (VALU pipe)
template <int CTRL>
static __device__ __forceinline__ float dppmv(float x) {
    return __int_as_float(__builtin_amdgcn_mov_dpp(__float_as_int(x), CTRL, 0xF, 0xF, true));
}
static __device__ __forceinline__ float rowsum16(float x) {
    x += dppmv<0xB1>(x);
    x += dppmv<0x4E>(x);
    x += dppmv<0x124>(x);
    x += dppmv<0x128>(x);
    return x;
}

// ---------------- fused prep: pe->bf16 (+zero pad), w_attn^T, w_proj^T -------
static __device__ __forceinline__ void tcvt_body(const float* __restrict__ src,
                                                 unsigned short* __restrict__ dst,
                                                 int R, int C, int gx, int gy,
                                                 float (*t)[65], int tid) {
    const int c0 = gx * 64, r0 = gy * 64;
    #pragma unroll
    for (int p = 0; p < 4; ++p) {
        const int i = tid + p * 256;
        const int r = i >> 4, c4 = (i & 15) * 4;
        const float4 v = *(const float4*)(src + (long)(r0 + r) * C + c0 + c4);
        t[r][c4] = v.x; t[r][c4+1] = v.y; t[r][c4+2] = v.z; t[r][c4+3] = v.w;
    }
    __syncthreads();
    #pragma unroll
    for (int p = 0; p < 4; ++p) {
        const int i = tid + p * 256;
        const int cr = i >> 4, r4 = (i & 15) * 4;
        ushort4 vv;
        vv.x = f2bf(t[r4+0][cr]); vv.y = f2bf(t[r4+1][cr]);
        vv.z = f2bf(t[r4+2][cr]); vv.w = f2bf(t[r4+3][cr]);
        *(ushort4*)(dst + (long)(c0 + cr) * R + r0 + r4) = vv;
    }
}

__global__ __launch_bounds__(256) void prep(const float* __restrict__ pe,
                                            unsigned short* __restrict__ peb,
                                            const float* __restrict__ wa,
                                            unsigned short* __restrict__ waT,
                                            const float* __restrict__ wp,
                                            unsigned short* __restrict__ wpT) {
    __shared__ float t[64][65];
    const int bx = blockIdx.x, tid = threadIdx.x;
    if (bx < 528) {                              // pe [8][2048][32] -> [8][2112][32] bf16, pad=0
        const int idx4 = bx * 256 + tid;         // ushort4 granules over [8][2112][8]
        const int h   = idx4 / 16896;
        const int rem = idx4 - h * 16896;
        const int u   = rem >> 3;
        const int d4  = (rem & 7) * 4;
        ushort4 o = make_ushort4(0, 0, 0, 0);
        if (u < TT) {
            const float4 v = *(const float4*)(pe + ((long)(h * TT + u)) * HD + d4);
            o.x = f2bf(v.x); o.y = f2bf(v.y); o.z = f2bf(v.z); o.w = f2bf(v.w);
        }
        *(ushort4*)(peb + ((long)(h * TTP + u)) * HD + d4) = o;
    } else if (bx < 576) {
        const int lo = bx - 528;                 // 48 blocks: w_attn [256][768] -> [768][256]
        tcvt_body(wa, waT, 256, 768, lo % 12, lo / 12, t, tid);
    } else {
        const int lo = bx - 576;                 // 16 blocks: w_proj transpose
        tcvt_body(wp, wpT, 256, 256, lo % 4, lo / 4, t, tid);
    }
}

// ---------------- Kernel A: MFMA qkv GEMM, fp32 A inline-converted -----------
// Q pre-scaled by (1/sqrt(32)) * log2(e) so attention uses raw exp2.
__global__ __launch_bounds__(256) void qkv_mfma(const float* __restrict__ xg,
                                                const unsigned short* __restrict__ Bg,
                                                unsigned short* __restrict__ Kb,
                                                unsigned short* __restrict__ Qb,
                                                unsigned short* __restrict__ Vt) {
    __shared__ unsigned short sm[13824];             // 27648 B
    unsigned short* As = sm;                         // [128][72]
    unsigned short* Bs = sm + 9216;                  // [64][72]
    const int tid = threadIdx.x;
    const int wv = tid >> 6, L = tid & 63;
    const int l15 = L & 15, q = L >> 4;
    const int n0 = blockIdx.x * 64;
    const int m0 = blockIdx.y * 128;

    f4 acc[2][4];
    #pragma unroll
    for (int mt = 0; mt < 2; ++mt)
        #pragma unroll
        for (int nt = 0; nt < 4; ++nt) acc[mt][nt] = (f4){0.f,0.f,0.f,0.f};

    for (int kc = 0; kc < 4; ++kc) {
        const int k0 = kc * 64;
        __syncthreads();
        #pragma unroll
        for (int p = 0; p < 4; ++p) {
            const int i = tid + p * 256;
            const int r = i >> 3, c = i & 7;
            const float4 va = *(const float4*)(xg + (long)(m0 + r) * 256 + k0 + c * 8);
            const float4 vb = *(const float4*)(xg + (long)(m0 + r) * 256 + k0 + c * 8 + 4);
            ushort4 lo, hi;
            lo.x = f2bf(va.x); lo.y = f2bf(va.y); lo.z = f2bf(va.z); lo.w = f2bf(va.w);
            hi.x = f2bf(vb.x); hi.y = f2bf(vb.y); hi.z = f2bf(vb.z); hi.w = f2bf(vb.w);
            *(ushort4*)(As + r * 72 + c * 8)     = lo;
            *(ushort4*)(As + r * 72 + c * 8 + 4) = hi;
        }
        #pragma unroll
        for (int p = 0; p < 2; ++p) {
            const int i = tid + p * 256;
            const int r = i >> 3, c = i & 7;
            *(bf8*)(Bs + r * 72 + c * 8) = *(const bf8*)(Bg + (long)(n0 + r) * 256 + k0 + c * 8);
        }
        __syncthreads();
        #pragma unroll
        for (int kk = 0; kk < 2; ++kk) {
            const bf8 a0 = *(const bf8*)(As + (wv * 32 + l15) * 72 + kk * 32 + q * 8);
            const bf8 a1 = *(const bf8*)(As + (wv * 32 + 16 + l15) * 72 + kk * 32 + q * 8);
            #pragma unroll
            for (int nt = 0; nt < 4; ++nt) {
                const bf8 bb = *(const bf8*)(Bs + (nt * 16 + l15) * 72 + kk * 32 + q * 8);
                acc[0][nt] = __builtin_amdgcn_mfma_f32_16x16x32_bf16(a0, bb, acc[0][nt], 0, 0, 0);
                acc[1][nt] = __builtin_amdgcn_mfma_f32_16x16x32_bf16(a1, bb, acc[1][nt], 0, 0, 0);
            }
        }
    }

    const int sec = n0 >> 8;                         // 0=K,1=Q,2=V
    #pragma unroll
    for (int mt = 0; mt < 2; ++mt) {
        const int gm = m0 + wv * 32 + mt * 16 + q * 4;
        const int b = gm >> 11, tb = gm & 2047;
        #pragma unroll
        for (int nt = 0; nt < 4; ++nt) {
            const int gn = n0 + nt * 16 + l15;
            const int cc = gn & 255, h = cc >> 5, d = cc & 31;
            const long bh = (long)b * NH + h;
            const f4 a = acc[mt][nt];
            if (sec == 2) {
                ushort4 vv;
                vv.x = f2bf(a[0]); vv.y = f2bf(a[1]); vv.z = f2bf(a[2]); vv.w = f2bf(a[3]);
                *(ushort4*)(Vt + (bh * HD + d) * TT + tb) = vv;
            } else if (sec == 1) {
                #pragma unroll
                for (int r = 0; r < 4; ++r)
                    Qb[(bh * TT + tb + r) * HD + d] = f2bf(a[r] * 0.25506655788696527f);
            } else {
                #pragma unroll
                for (int r = 0; r < 4; ++r)
                    Kb[(bh * TT + tb + r) * HD + d] = f2bf(a[r]);
            }
        }
    }
}

// ---------------- Kernel B: MFMA flash attention, static-max softmax ---------
// Round-0 structure (two independent halves, balanced blocks) plus:
//  * T14 async-STAGE: next tile's K/V/PE global loads issue BEFORE compute of
//    the current tile (into registers); ds_write lands after the barrier.
//  * Psw stride 76: conflict-free b16 P scatter (24q bank rotation).
//  * 12-bpermute skew gather (3 packed words per r serve all 4 nb).
__global__ __launch_bounds__(256) void attn_kernel(const unsigned short* __restrict__ Kb,
                                                   const unsigned short* __restrict__ Qb,
                                                   const unsigned short* __restrict__ Vtg,
                                                   const unsigned short* __restrict__ peb,
                                                   unsigned short* __restrict__ po,
                                                   float* __restrict__ pl) {
    __shared__ unsigned short lds[14848];            // 29696 B
    unsigned short* Ks  = lds;                       // [64][40]  K tile
    unsigned short* PEs = lds + 2560;                // [128][40] pe band
    unsigned short* Vts = lds + 7680;                // [32][72]  V^T tile
    unsigned short* Psw = lds + 9984 + (threadIdx.x >> 6) * 1216;  // [16][76] per wave

    const int tid = threadIdx.x;
    const int wv  = tid >> 6;
    const int L   = tid & 63;
    const int l15 = L & 15;
    const int q   = L >> 4;
    const int pair = blockIdx.x >> 1;
    const int sblk = blockIdx.x & 1;
    const int h = blockIdx.y, b = blockIdx.z;
    const long bh = (long)b * NH + h;
    const unsigned short* Kg = Kb  + bh * TT * HD;
    const unsigned short* Qg = Qb  + bh * TT * HD;
    const unsigned short* Vg = Vtg + bh * HD * TT;
    const unsigned short* Pg = peb + (long)h * TTP * HD;

    const int krow = tid >> 2, kc = tid & 3;         // K/PE staging coords
    const int vrow = tid >> 3, vc = tid & 7;         // V staging coords
    const f4 z4 = {0.f, 0.f, 0.f, 0.f};
    const f4 m4 = {-16.f, -16.f, -16.f, -16.f};      // static softmax max

    // hoisted skew-gather controls (per r): source lane + perm half-selects
    int saddr[4]; unsigned pselL[4], pselX[4];
    #pragma unroll
    for (int r = 0; r < 4; ++r) {
        const int tcol = l15 + 15 - 4 * q - r;       // 0..30
        saddr[r] = ((q << 4) | (tcol & 15)) << 2;
        const bool c = tcol >= 16;
        pselL[r] = c ? 0x03020C0Cu : 0x01000C0Cu;    // intra-word: hi : lo
        pselX[r] = c ? 0x05040C0Cu : 0x03020C0Cu;    // cross-word: a.lo : b.hi
    }

    for (int half = 0; half < 2; ++half) {
        const int itile = half ? 31 - pair : pair;
        const int t0 = itile * 64;

        const bf8 aq = *(const bf8*)(Qg + (t0 + wv * 16 + l15) * HD + q * 8);
        f4 o0 = z4, o1 = z4;
        float l_st[4] = {0.f, 0.f, 0.f, 0.f};

        // prefetch first tile's staging data into registers
        bf8 ck, cv, cp0, cp1;
        if (sblk <= itile) {
            const int s0 = sblk * 64;
            const int ub = TT - 64 - t0 + s0;
            ck  = *(const bf8*)(Kg + (s0 + krow) * HD + kc * 8);
            cv  = *(const bf8*)(Vg + vrow * TT + s0 + vc * 8);
            cp0 = *(const bf8*)(Pg + (long)(ub + krow) * HD + kc * 8);
            cp1 = *(const bf8*)(Pg + (long)(ub + 64 + krow) * HD + kc * 8);
        }

        for (int jt = sblk; jt <= itile; jt += 2) {
            __syncthreads();                         // prior compute done reading LDS
            *(bf8*)(Ks  + krow * 40 + kc * 8)        = ck;
            *(bf8*)(Vts + vrow * 72 + vc * 8)        = cv;
            *(bf8*)(PEs + krow * 40 + kc * 8)        = cp0;
            *(bf8*)(PEs + (krow + 64) * 40 + kc * 8) = cp1;
            __syncthreads();

            // issue next tile's global loads; latency hides under compute below
            if (jt + 2 <= itile) {
                const int s0n = (jt + 2) * 64;
                const int ubn = TT - 64 - t0 + s0n;
                ck  = *(const bf8*)(Kg + (s0n + krow) * HD + kc * 8);
                cv  = *(const bf8*)(Vg + vrow * TT + s0n + vc * 8);
                cp0 = *(const bf8*)(Pg + (long)(ubn + krow) * HD + kc * 8);
                cp1 = *(const bf8*)(Pg + (long)(ubn + 64 + krow) * HD + kc * 8);
            }

            // ---- QK^T (acc init = -16 static max) and Q@pe ----
            f4 sa[4], ra[5];
            #pragma unroll
            for (int nt = 0; nt < 4; ++nt) {
                const bf8 bk = *(const bf8*)(Ks + (nt * 16 + l15) * 40 + q * 8);
                sa[nt] = __builtin_amdgcn_mfma_f32_16x16x32_bf16(aq, bk, m4, 0, 0, 0);
            }
            const int pebase = 48 - 16 * wv;
            #pragma unroll
            for (int nt = 0; nt < 5; ++nt) {
                const bf8 bp = *(const bf8*)(PEs + (pebase + nt * 16 + l15) * 40 + q * 8);
                ra[nt] = __builtin_amdgcn_mfma_f32_16x16x32_bf16(aq, bp, z4, 0, 0, 0);
            }

            // ---- skew gather: 3 packed words per r serve all 4 nb ----
            #pragma unroll
            for (int r = 0; r < 4; ++r) {
                const unsigned w0 = __builtin_amdgcn_perm(
                    (unsigned)__float_as_int(ra[1][r]), (unsigned)__float_as_int(ra[0][r]), 0x07060302u);
                const unsigned w1 = __builtin_amdgcn_perm(
                    (unsigned)__float_as_int(ra[3][r]), (unsigned)__float_as_int(ra[2][r]), 0x07060302u);
                const unsigned w2 = ((unsigned)__float_as_int(ra[4][r])) >> 16;
                const int v0 = __builtin_amdgcn_ds_bpermute(saddr[r], (int)w0);
                const int v1 = __builtin_amdgcn_ds_bpermute(saddr[r], (int)w1);
                const int v2 = __builtin_amdgcn_ds_bpermute(saddr[r], (int)w2);
                sa[0][r] += __int_as_float((int)__builtin_amdgcn_perm((unsigned)v0, (unsigned)v0, pselL[r]));
                sa[1][r] += __int_as_float((int)__builtin_amdgcn_perm((unsigned)v1, (unsigned)v0, pselX[r]));
                sa[2][r] += __int_as_float((int)__builtin_amdgcn_perm((unsigned)v1, (unsigned)v1, pselL[r]));
                sa[3][r] += __int_as_float((int)__builtin_amdgcn_perm((unsigned)v2, (unsigned)v1, pselX[r]));
            }

            if (jt == itile) {                       // causal mask (diagonal tile)
                #pragma unroll
                for (int nb = 0; nb < 4; ++nb)
                    #pragma unroll
                    for (int r = 0; r < 4; ++r) {
                        const int s_l = nb * 16 + l15;
                        const int t_l = wv * 16 + 4 * q + r;
                        if (s_l > t_l) sa[nb][r] = -1e30f;
                    }
            }

            // ---- static-max softmax: p = exp2(sa); accumulate l per lane ----
            #pragma unroll
            for (int r = 0; r < 4; ++r) {
                #pragma unroll
                for (int nb = 0; nb < 4; ++nb) {
                    const float p = exp2f(sa[nb][r]);
                    l_st[r] += p;
                    const unsigned pu = (unsigned)__float_as_int(p);
                    Psw[(4 * q + r) * 76 + nb * 16 + l15] =
                        (unsigned short)((pu + 0x8000u) >> 16);
                }
            }

            // ---- PV: O += P @ V ----
            #pragma unroll
            for (int ks = 0; ks < 2; ++ks) {
                const bf8 ap  = *(const bf8*)(Psw + l15 * 76 + ks * 32 + q * 8);
                const bf8 bv0 = *(const bf8*)(Vts + l15 * 72 + ks * 32 + q * 8);
                const bf8 bv1 = *(const bf8*)(Vts + (16 + l15) * 72 + ks * 32 + q * 8);
                o0 = __builtin_amdgcn_mfma_f32_16x16x32_bf16(ap, bv0, o0, 0, 0, 0);
                o1 = __builtin_amdgcn_mfma_f32_16x16x32_bf16(ap, bv1, o1, 0, 0, 0);
            }
        }

        // ---- epilogue: raw partial O (bf16) + row l ----
        const long pt = (bh * 32 + itile) * 2 + sblk;
        unsigned short* pob = po + pt * 2048;
        #pragma unroll
        for (int r = 0; r < 4; ++r) {
            const int row = wv * 16 + 4 * q + r;
            pob[row * 32 + l15]      = f2bf(o0[r]);
            pob[row * 32 + 16 + l15] = f2bf(o1[r]);
            const float ls = rowsum16(l_st[r]);
            if (l15 == 0) pl[pt * 64 + row] = ls;
        }
    }
}

// ---------------- merge s-split partials -> bf16 att -------------------------
__global__ __launch_bounds__(256) void attn_merge(const unsigned short* __restrict__ po,
                                                  const float* __restrict__ pl,
                                                  unsigned short* __restrict__ attb) {
    const int i = blockIdx.x * 256 + threadIdx.x;    // 524288 quads
    const int d4   = i & 7;
    const int row  = (i >> 3) & 63;
    const int tile = (i >> 9) & 31;
    const int bh   = i >> 14;
    const int h = bh & 7, b = bh >> 3;
    const long pt0 = ((long)bh * 32 + tile) * 2;
    const float l0 = pl[pt0 * 64 + row], l1 = pl[(pt0 + 1) * 64 + row];
    const float inv = 1.0f / (l0 + l1);
    const ushort4 a = *(const ushort4*)(po + pt0 * 2048 + row * 32 + d4 * 4);
    const ushort4 c = *(const ushort4*)(po + (pt0 + 1) * 2048 + row * 32 + d4 * 4);
    ushort4 o;
    o.x = f2bf((bf2f(a.x) + bf2f(c.x)) * inv);
    o.y = f2bf((bf2f(a.y) + bf2f(c.y)) * inv);
    o.z = f2bf((bf2f(a.z) + bf2f(c.z)) * inv);
    o.w = f2bf((bf2f(a.w) + bf2f(c.w)) * inv);
    const int t = tile * 64 + row;
    *(ushort4*)(attb + ((long)(b * TT + t)) * NEMB + h * HD + d4 * 4) = o;
}

// ---------------- Kernel C: MFMA proj GEMM + bias ----------------------------
__global__ __launch_bounds__(256) void proj_mfma(const unsigned short* __restrict__ Ag,
                                                 const unsigned short* __restrict__ Bg,
                                                 const float* __restrict__ bias,
                                                 float* __restrict__ out) {
    __shared__ unsigned short sm[13824];
    unsigned short* As = sm;                         // [128][72]
    unsigned short* Bs = sm + 9216;                  // [64][72]
    const int tid = threadIdx.x;
    const int wv = tid >> 6, L = tid & 63;
    const int l15 = L & 15, q = L >> 4;
    const int n0 = blockIdx.x * 64;
    const int m0 = blockIdx.y * 128;

    f4 acc[2][4];
    #pragma unroll
    for (int mt = 0; mt < 2; ++mt)
        #pragma unroll
        for (int nt = 0; nt < 4; ++nt) acc[mt][nt] = (f4){0.f,0.f,0.f,0.f};

    for (int kc = 0; kc < 4; ++kc) {
        const int k0 = kc * 64;
        __syncthreads();
        #pragma unroll
        for (int p = 0; p < 4; ++p) {
            const int i = tid + p * 256;
            const int r = i >> 3, c = i & 7;
            *(bf8*)(As + r * 72 + c * 8) = *(const bf8*)(Ag + (long)(m0 + r) * 256 + k0 + c * 8);
        }
        #pragma unroll
        for (int p = 0; p < 2; ++p) {
            const int i = tid + p * 256;
            const int r = i >> 3, c = i & 7;
            *(bf8*)(Bs + r * 72 + c * 8) = *(const bf8*)(Bg + (long)(n0 + r) * 256 + k0 + c * 8);
        }
        __syncthreads();
        #pragma unroll
        for (int kk = 0; kk < 2; ++kk) {
            const bf8 a0 = *(const bf8*)(As + (wv * 32 + l15) * 72 + kk * 32 + q * 8);
            const bf8 a1 = *(const bf8*)(As + (wv * 32 + 16 + l15) * 72 + kk * 32 + q * 8);
            #pragma unroll
            for (int nt = 0; nt < 4; ++nt) {
                const bf8 bb = *(const bf8*)(Bs + (nt * 16 + l15) * 72 + kk * 32 + q * 8);
                acc[0][nt] = __builtin_amdgcn_mfma_f32_16x16x32_bf16(a0, bb, acc[0][nt], 0, 0, 0);
                acc[1][nt] = __builtin_amdgcn_mfma_f32_16x16x32_bf16(a1, bb, acc[1][nt], 0, 0, 0);
            }
        }
    }

    #pragma unroll
    for (int mt = 0; mt < 2; ++mt) {
        const int gm = m0 + wv * 32 + mt * 16 + q * 4;
        #pragma unroll
        for (int nt = 0; nt < 4; ++nt) {
            const int gn = n0 + nt * 16 + l15;
            const float bv = bias[gn];
            #pragma unroll
            for (int r = 0; r < 4; ++r)
                out[(long)(gm + r) * NEMB + gn] = acc[mt][nt][r] + bv;
        }
    }
}

extern "C" void kernel_launch(void* const* d_in, const int* in_sizes, int n_in,
                              void* d_out, int out_size, void* d_ws, size_t ws_size,
                              hipStream_t stream) {
    const float* x      = (const float*)d_in[0];
    const float* w_attn = (const float*)d_in[1];
    const float* pe     = (const float*)d_in[2];
    const float* w_proj = (const float*)d_in[3];
    const float* b_proj = (const float*)d_in[4];
    float* out = (float*)d_out;

    char* base = (char*)d_ws;
    unsigned short* Kb   = (unsigned short*)(base);                        // 4 MB
    unsigned short* Qb   = (unsigned short*)(base + ( 4u << 20));          // 4 MB
    unsigned short* Vt   = (unsigned short*)(base + ( 8u << 20));          // 4 MB
    unsigned short* attb = (unsigned short*)(base + (12u << 20));          // 4 MB
    unsigned short* peb  = (unsigned short*)(base + (16u << 20));          // 1.03 MB
    unsigned short* waT  = (unsigned short*)(base + (18u << 20));          // 384 KB
    unsigned short* wpT  = (unsigned short*)(base + (37u << 19));          // 128 KB @18.5MB
    unsigned short* po   = (unsigned short*)(base + (19u << 20));          // 8 MB
    float*          pl   = (float*)        (base + (27u << 20));           // 512 KB

    prep<<<dim3(592), 256, 0, stream>>>(pe, peb, w_attn, waT, w_proj, wpT);
    qkv_mfma<<<dim3(12, 64), 256, 0, stream>>>(x, waT, Kb, Qb, Vt);
    attn_kernel<<<dim3(32, NH, BB), 256, 0, stream>>>(Kb, Qb, Vt, peb, po, pl);
    attn_merge<<<dim3(2048), 256, 0, stream>>>(po, pl, attb);
    proj_mfma<<<dim3(4, 64), 256, 0, stream>>>(attb, wpT, b_proj, out);
}